// Round 1
// 295.131 us; speedup vs baseline: 1.1234x; 1.1234x over previous
//
#include <hip/hip_runtime.h>
#include <stdint.h>

typedef _Float16 f16;
typedef _Float16 f16x2 __attribute__((ext_vector_type(2)));
typedef _Float16 f16x4 __attribute__((ext_vector_type(4)));
typedef _Float16 f16x8 __attribute__((ext_vector_type(8)));
typedef float f32x4 __attribute__((ext_vector_type(4)));

typedef __attribute__((address_space(1))) void gvoid;
typedef __attribute__((address_space(3))) void lvoid;

#define NROWS 4096
#define DIMIN 1536
#define DMLP 512
#define FDIM 256
#define NCLS 10000
#define NPAD 10112   // 79 * 128
#define NBMW 320     // bitmap words (>= ceil(NCLS/32)=313)

__device__ __forceinline__ void load_lds16(const void* g, void* l) {
    // async global->LDS, 16B per lane; LDS dest = wave-uniform base + lane*16
    __builtin_amdgcn_global_load_lds((gvoid*)g, (lvoid*)l, 16, 0, 0);
}

// ---------------------------------------------------------------------------
// fp16 GEMM: C[M,N] = A[M,K] @ Bt[N,K]^T (+bias).
// Tile TM x TN per block (256 thr = 4 waves in 2x2), BK=64.
// 2-phase double-buffered pipeline (T3 minimum): issue next K-tile's
// global_load_lds BEFORE computing the current tile, ONE __syncthreads per
// K-step (its implicit vmcnt(0) drain lands after compute has hidden the
// load latency).
// LDS layout per buffer: A then B, row-major [row][64k], 128 B row stride,
// XOR swizzle: logical 16B-group g of row r lives at slot g ^ (r & 7).
// Staging keeps LDS linear (global_load_lds requires base+lane*16) and
// permutes the GLOBAL source address instead.
// STATS: fuse BatchNorm column sum/sumsq (atomicAdd) into the epilogue.
// NT: non-temporal C stores (streaming output, keep L2 for operands).
// ---------------------------------------------------------------------------
template<int TM, int TN, bool STATS, bool NT>
__global__ __launch_bounds__(256) void gemm_t(
    const f16* __restrict__ A, const f16* __restrict__ Bt,
    float* __restrict__ C, const float* __restrict__ bias,
    int K, int ldc, int Nstore,
    float* __restrict__ sums, float* __restrict__ sqs)
{
    constexpr int BK = 64;
    constexpr int AM = TM / 32;       // 16-row tiles per wave (m)
    constexpr int AN = TN / 32;       // 16-col tiles per wave (n)
    constexpr int CA = TM * 8;        // A 16B-chunks per K-tile
    constexpr int CB = TN * 8;
    constexpr int RTOT = (CA + CB) / 256;
    constexpr int SPAN = (TM + TN) * BK;   // f16 elems per buffer
    static_assert(CA % 256 == 0, "A/B staging split must be round-aligned");

    __shared__ f16 smem[2 * SPAN];

    const int tid  = threadIdx.x;
    const int lane = tid & 63;
    const int w    = tid >> 6;
    const int wm   = (w >> 1) * (TM / 2);
    const int wn   = (w & 1) * (TN / 2);
    const int row0 = blockIdx.x * TM;
    const int col0 = blockIdx.y * TN;
    const int quad = lane >> 4;
    const int r16  = lane & 15;

    f32x4 acc[AM][AN] = {};

    // per-round staging descriptors (compile-time A/B split)
    const f16* gsrc[RTOT];
    int ldsoff[RTOT];
#pragma unroll
    for (int r = 0; r < RTOT; ++r) {
        int c = tid + r * 256;
        bool isA = (c < CA);
        int cc = isA ? c : c - CA;
        int row = cc >> 3;
        int gs = (cc & 7) ^ (row & 7);        // swizzled source group
        gsrc[r] = (isA ? A + (size_t)(row0 + row) * K
                       : Bt + (size_t)(col0 + row) * K) + gs * 8;
        ldsoff[r] = (isA ? 0 : TM * BK) + cc * 8;   // LDS stays linear
    }

    const int nt = K / BK;

    // prologue: stage tile 0 into buffer 0
#pragma unroll
    for (int r = 0; r < RTOT; ++r)
        load_lds16(gsrc[r], smem + ldsoff[r]);
    __syncthreads();

    int buf = 0;
    for (int t = 0; t < nt; ++t) {
        // issue next tile's loads into the other buffer (hidden under MFMA)
        if (t + 1 < nt) {
            const int k0 = (t + 1) * BK;
            const int o = (buf ^ 1) * SPAN;
#pragma unroll
            for (int r = 0; r < RTOT; ++r)
                load_lds16(gsrc[r] + k0, smem + o + ldsoff[r]);
        }
        const f16* As = smem + buf * SPAN;
        const f16* Bs = As + TM * BK;
#pragma unroll
        for (int ks = 0; ks < 2; ++ks) {
            f16x8 af[AM], bq[AN];
#pragma unroll
            for (int mi = 0; mi < AM; ++mi) {
                int row = wm + mi * 16 + r16;
                int slot = (ks * 4 + quad) ^ (r16 & 7);
                af[mi] = *(const f16x8*)&As[row * BK + slot * 8];
            }
#pragma unroll
            for (int ni = 0; ni < AN; ++ni) {
                int row = wn + ni * 16 + r16;
                int slot = (ks * 4 + quad) ^ (r16 & 7);
                bq[ni] = *(const f16x8*)&Bs[row * BK + slot * 8];
            }
#pragma unroll
            for (int mi = 0; mi < AM; ++mi)
#pragma unroll
                for (int ni = 0; ni < AN; ++ni)
                    acc[mi][ni] = __builtin_amdgcn_mfma_f32_16x16x32_f16(
                        af[mi], bq[ni], acc[mi][ni], 0, 0, 0);
        }
        __syncthreads();   // implicit vmcnt(0): next tile has landed
        buf ^= 1;
    }

    // C/D layout: col = lane&15, row = quad*4 + reg
#pragma unroll
    for (int ni = 0; ni < AN; ++ni) {
        int col = col0 + wn + ni * 16 + r16;
        float bv = bias ? bias[col] : 0.0f;
        float s = 0.0f, q = 0.0f;
        if (col < Nstore) {
#pragma unroll
            for (int mi = 0; mi < AM; ++mi) {
                int rowb = row0 + wm + mi * 16 + quad * 4;
#pragma unroll
                for (int r = 0; r < 4; ++r) {
                    float v = acc[mi][ni][r] + bv;
                    if constexpr (NT)
                        __builtin_nontemporal_store(v, &C[(size_t)(rowb + r) * ldc + col]);
                    else
                        C[(size_t)(rowb + r) * ldc + col] = v;
                    if constexpr (STATS) { s += v; q += v * v; }
                }
            }
        }
        if constexpr (STATS) {
            // reduce across the 4 quads (lanes differing in bits 4..5)
            s += __shfl_xor(s, 16); s += __shfl_xor(s, 32);
            q += __shfl_xor(q, 16); q += __shfl_xor(q, 32);
            if (quad == 0) {
                atomicAdd(&sums[col], s);
                atomicAdd(&sqs[col], q);
            }
        }
    }
}

// ---------------------------------------------------------------------------
__global__ void zero_k(float* __restrict__ p, int n) {
    int i = blockIdx.x * 256 + threadIdx.x;
    if (i < n) p[i] = 0.0f;
}

__global__ void f32_to_f16_k(const float* __restrict__ in, f16* __restrict__ out, int n4) {
    int i = blockIdx.x * 256 + threadIdx.x;
    if (i >= n4) return;
    float4 v = *(const float4*)&in[(size_t)i * 4];
    f16x4 o = {(f16)v.x, (f16)v.y, (f16)v.z, (f16)v.w};
    *(f16x4*)&out[(size_t)i * 4] = o;
}

// tiled transpose: in [R,C] fp32 -> out [C,R] fp16; 32x32 tiles, 256 thr
__global__ void transpose_f16_tile_k(const float* __restrict__ in, f16* __restrict__ out,
                                     int R, int C) {
    __shared__ float t[32][33];
    int tx = threadIdx.x & 31, ty = threadIdx.x >> 5;   // 32x8
    int c0 = blockIdx.x * 32, r0 = blockIdx.y * 32;
#pragma unroll
    for (int k = 0; k < 4; ++k)
        t[ty + k * 8][tx] = in[(size_t)(r0 + ty + k * 8) * C + c0 + tx];
    __syncthreads();
#pragma unroll
    for (int k = 0; k < 4; ++k)
        out[(size_t)(c0 + ty + k * 8) * R + r0 + tx] = (f16)t[tx][ty + k * 8];
}

// mark touched classes: bm bit y set iff y appears in label[0..4095]
__global__ void touch_k(const int* __restrict__ label, unsigned int* __restrict__ bm) {
    int i = blockIdx.x * 256 + threadIdx.x;
    int y = label[i];
    atomicOr(&bm[y >> 5], 1u << (y & 31));
}

// fold BN stats into per-column scale/shift (512 threads total)
__global__ void bn_finish_k(const float* __restrict__ sums, const float* __restrict__ sqs,
                            const float* __restrict__ gamma, const float* __restrict__ beta,
                            float* __restrict__ scale, float* __restrict__ shift) {
    int c = blockIdx.x * 256 + threadIdx.x;
    if (c >= DMLP) return;
    const float inv_n = 1.0f / 4096.0f;
    float mu = sums[c] * inv_n;
    float var = fmaxf(sqs[c] * inv_n - mu * mu, 0.0f);
    float a = rsqrtf(var + 1e-5f) * gamma[c];
    scale[c] = a;
    shift[c] = beta[c] - mu * a;
}

// BN apply + ReLU + cast to fp16; 4 elems/thread (float4)
__global__ void bn_apply_k(const float* __restrict__ h, const float* __restrict__ scale,
                           const float* __restrict__ shift, f16* __restrict__ out) {
    int i = blockIdx.x * 256 + threadIdx.x;     // over 4096*512/4
    int c = (i & 127) * 4;
    float4 v = *(const float4*)&h[(size_t)i * 4];
    float4 sc = *(const float4*)&scale[c];
    float4 sh = *(const float4*)&shift[c];
    f16x4 o = {(f16)fmaxf(v.x * sc.x + sh.x, 0.0f),
               (f16)fmaxf(v.y * sc.y + sh.y, 0.0f),
               (f16)fmaxf(v.z * sc.z + sh.z, 0.0f),
               (f16)fmaxf(v.w * sc.w + sh.w, 0.0f)};
    *(f16x4*)&out[(size_t)i * 4] = o;
}

// row-wise L2 normalize out2[4096,256] -> feat fp32 + fp16; one wave/row
__global__ void l2norm_k(const float* __restrict__ X, float* __restrict__ Y, f16* __restrict__ Yh) {
    int wv = (blockIdx.x * 256 + threadIdx.x) >> 6;
    int lane = threadIdx.x & 63;
    float4 v = *(const float4*)&X[(size_t)wv * FDIM + lane * 4];
    float s = v.x * v.x + v.y * v.y + v.z * v.z + v.w * v.w;
#pragma unroll
    for (int off = 32; off > 0; off >>= 1) s += __shfl_xor(s, off);
    float inv = 1.0f / fmaxf(sqrtf(s), 1e-12f);
    float4 o = {v.x * inv, v.y * inv, v.z * inv, v.w * inv};
    *(float4*)&Y[(size_t)wv * FDIM + lane * 4] = o;
    f16x4 oh = {(f16)o.x, (f16)o.y, (f16)o.z, (f16)o.w};
    *(f16x4*)&Yh[(size_t)wv * FDIM + lane * 4] = oh;
}

// per-label sequential momentum chain + f16 memory-bank materialization.
// One wave per padded row; rows >= NCLS -> zeros; untouched rows (bitmap
// gate, ~66% of classes) skip the 64-iteration label scan entirely.
__global__ void chain_k(const int* __restrict__ label, const float* __restrict__ feat,
                        const float* __restrict__ mp, const unsigned int* __restrict__ bm,
                        f16* __restrict__ memh) {
    int y = (blockIdx.x * 256 + threadIdx.x) >> 6;
    int lane = threadIdx.x & 63;
    float4 m = {0.f, 0.f, 0.f, 0.f};
    if (y < NCLS) {
        m = *(const float4*)&mp[(size_t)y * FDIM + lane * 4];
        if ((bm[y >> 5] >> (y & 31)) & 1u) {
            for (int g = 0; g < 64; ++g) {
                int lab = label[g * 64 + lane];
                unsigned long long mask = __ballot(lab == y);
                while (mask) {
                    int b = __builtin_ctzll(mask);
                    mask &= mask - 1;
                    int i = g * 64 + b;
                    float4 x = *(const float4*)&feat[(size_t)i * FDIM + lane * 4];
                    m.x = 0.9f * m.x + 0.1f * x.x;
                    m.y = 0.9f * m.y + 0.1f * x.y;
                    m.z = 0.9f * m.z + 0.1f * x.z;
                    m.w = 0.9f * m.w + 0.1f * x.w;
                    float s = m.x * m.x + m.y * m.y + m.z * m.z + m.w * m.w;
#pragma unroll
                    for (int off = 32; off > 0; off >>= 1) s += __shfl_xor(s, off);
                    float inv = 1.0f / fmaxf(sqrtf(s), 1e-12f);
                    m.x *= inv; m.y *= inv; m.z *= inv; m.w *= inv;
                }
            }
        }
    }
    f16x4 o = {(f16)m.x, (f16)m.y, (f16)m.z, (f16)m.w};
    *(f16x4*)&memh[(size_t)y * FDIM + lane * 4] = o;
}

// ---------------------------------------------------------------------------
extern "C" void kernel_launch(void* const* d_in, const int* in_sizes, int n_in,
                              void* d_out, int out_size, void* d_ws, size_t ws_size,
                              hipStream_t stream) {
    const float* feat_in = (const float*)d_in[0];
    const int*   label   = (const int*)d_in[1];
    const float* W1      = (const float*)d_in[2];
    const float* b1      = (const float*)d_in[3];
    const float* gamma   = (const float*)d_in[4];
    const float* beta    = (const float*)d_in[5];
    const float* W2      = (const float*)d_in[6];
    const float* b2      = (const float*)d_in[7];
    const float* mp      = (const float*)d_in[8];
    float* out = (float*)d_out;

    char* w = (char*)d_ws;
    f16* A1h   = (f16*)w;   w += (size_t)NROWS * DIMIN * 2;   // 12.6 MB
    f16* W1t   = (f16*)w;   w += (size_t)DMLP * DIMIN * 2;    // 1.6 MB
    f16* W2t   = (f16*)w;   w += (size_t)FDIM * DMLP * 2;     // 0.26 MB
    float* h   = (float*)w; w += (size_t)NROWS * DMLP * 4;    // 8.4 MB
    f16* h2    = (f16*)w;   w += (size_t)NROWS * DMLP * 2;    // 4.2 MB
    float* out2= (float*)w; w += (size_t)NROWS * FDIM * 4;    // 4.2 MB
    float* feat= (float*)w; w += (size_t)NROWS * FDIM * 4;    // 4.2 MB
    f16* feath = (f16*)w;   w += (size_t)NROWS * FDIM * 2;    // 2.1 MB
    f16* memh  = (f16*)w;   w += (size_t)NPAD * FDIM * 2;     // 5.2 MB
    float* sums= (float*)w; w += DMLP * 4;
    float* sqs = (float*)w; w += DMLP * 4;
    unsigned int* bm = (unsigned int*)w; w += NBMW * 4;       // touched bitmap
    float* bnsc= (float*)w; w += DMLP * 4;
    float* bnsh= (float*)w; w += DMLP * 4;

    // stage 0: zero stats+bitmap (contiguous), mark touched classes, convert
    zero_k<<<6, 256, 0, stream>>>(sums, 2 * DMLP + NBMW);
    touch_k<<<NROWS / 256, 256, 0, stream>>>(label, bm);
    f32_to_f16_k<<<(NROWS * DIMIN / 4) / 256, 256, 0, stream>>>(feat_in, A1h, NROWS * DIMIN / 4);
    {
        dim3 g1(DMLP / 32, DIMIN / 32);       // W1 [1536,512] -> W1t [512,1536]
        transpose_f16_tile_k<<<g1, 256, 0, stream>>>(W1, W1t, DIMIN, DMLP);
        dim3 g2(FDIM / 32, DMLP / 32);        // W2 [512,256] -> W2t [256,512]
        transpose_f16_tile_k<<<g2, 256, 0, stream>>>(W2, W2t, DMLP, FDIM);
    }

    // GEMM1: h = feat_in @ W1 + b1, BN stats fused (128x64 tiles -> 256 blocks)
    {
        dim3 g(NROWS / 128, DMLP / 64);
        gemm_t<128, 64, true, false><<<g, 256, 0, stream>>>(
            A1h, W1t, h, b1, DIMIN, DMLP, DMLP, sums, sqs);
    }

    // BN finish + apply
    bn_finish_k<<<2, 256, 0, stream>>>(sums, sqs, gamma, beta, bnsc, bnsh);
    bn_apply_k<<<(NROWS * DMLP / 4) / 256, 256, 0, stream>>>(h, bnsc, bnsh, h2);

    // GEMM2: out2 = h2 @ W2 + b2    (64x64 tiles -> 256 blocks)
    {
        dim3 g(NROWS / 64, FDIM / 64);
        gemm_t<64, 64, false, false><<<g, 256, 0, stream>>>(
            h2, W2t, out2, b2, DMLP, FDIM, FDIM, nullptr, nullptr);
    }

    // feat = l2norm(out2)
    l2norm_k<<<NROWS / 4, 256, 0, stream>>>(out2, feat, feath);

    // memory bank: per-label chains (bitmap-gated) + f16 materialization
    chain_k<<<NPAD / 4, 256, 0, stream>>>(label, feat, mp, bm, memh);

    // GEMM3: sim = feat @ mem^T   [4096, 10000]  (128x128 tiles -> 2528 blocks,
    // non-temporal C stores: don't let the 164 MB stream evict memh/feath)
    {
        dim3 g(NROWS / 128, NPAD / 128);
        gemm_t<128, 128, false, true><<<g, 256, 0, stream>>>(
            feath, memh, out, nullptr, FDIM, NCLS, NCLS, nullptr, nullptr);
    }
}